// Round 3
// baseline (116.070 us; speedup 1.0000x reference)
//
#include <hip/hip_runtime.h>

#define B 8
#define C 4
#define H 384
#define W 384
#define HW (H * W)
#define CHW (C * H * W)
#define NTOT (B * CHW)        // 4,718,592
#define BIG2 589824           // 768^2, reference's BIG cap squared
#define TPI 576               // tiles per image (12x48 of 32x8)
#define NBLK (B * TPI)        // 4608
#define NSEG (B * H * 6)      // 18432 row-segments of 64 px
#define LOG2E 1.44269504088896340736f

// min over set bits p of (p - lx)^2 ; 999 sentinel if empty side. lx in [16,48).
__device__ __forceinline__ int nearest2(unsigned long long m, int lx, int shl) {
    unsigned long long right = m >> lx;
    int dR = right ? (int)__builtin_ctzll(right) : 999;
    unsigned long long leftb = m << shl;            // shl = 63 - lx
    int dL = leftb ? (int)__builtin_clzll(leftb) : 999;
    int d = min(dR, dL);
    return d * d;
}

// Exact Chebyshev-ring global-memory scan (essentially never taken).
__device__ __attribute__((noinline))
int ring_fallback(const int* __restrict__ tg, int xa, int ya, int c, int best) {
    for (int d = 17; d * d < best; ++d) {
        int xlo = xa - d, xhi = xa + d, ylo = ya - d, yhi = ya + d;
        for (int xx = max(xlo, 0); xx <= min(xhi, W - 1); ++xx) {
            int ddx = xx - xa;
            int bb = ddx * ddx + d * d;
            if (bb < best) {
                if (ylo >= 0 && tg[ylo * W + xx] == c) best = bb;
                if (yhi < H && tg[yhi * W + xx] == c) best = min(best, bb);
            }
        }
        for (int yy = max(ylo + 1, 0); yy <= min(yhi - 1, H - 1); ++yy) {
            int ddy = yy - ya;
            int bb = ddy * ddy + d * d;
            if (bb < best) {
                if (xlo >= 0 && tg[yy * W + xlo] == c) best = bb;
                if (xhi < W && tg[yy * W + xhi] == c) best = min(best, bb);
            }
        }
    }
    return best;
}

// Build per-class row bitmasks once: masks[(b*H+y)*24 + c*6 + word].
// One wave per 64-px row segment; 4 ballots; lane0 writes 4 u64.
__global__ __launch_bounds__(256)
void build_masks(const int* __restrict__ targets,
                 unsigned long long* __restrict__ masks) {
    int wv = threadIdx.x >> 6, lane = threadIdx.x & 63;
    int seg = blockIdx.x * 4 + wv;
    if (seg >= NSEG) return;
    int wd = seg % 6, rem = seg / 6;          // rem = b*H + y
    int tv = targets[rem * W + wd * 64 + lane];
    unsigned long long m0 = __ballot(tv == 0);
    unsigned long long m1 = __ballot(tv == 1);
    unsigned long long m2 = __ballot(tv == 2);
    unsigned long long m3 = __ballot(tv == 3);
    if (lane == 0) {
        unsigned long long* dst = masks + (size_t)rem * 24 + wd;
        dst[0]  = m0;
        dst[6]  = m1;
        dst[12] = m2;
        dst[18] = m3;
    }
}

// One 256-thread block per 32x8 tile, 1 px/thread (4608 blocks -> 18432
// waves, >2x machine wave capacity: latency-bound fix). Staging: threads
// 0..159 funnel-shift one 64-bit (row, class) window from the global masks
// (2 u64 loads each; no ballots, no edge path). LDS ~2.6 KB -> 8 blocks/CU.
__global__ __launch_bounds__(256)
void dist_loss_kernel(const float* __restrict__ outputs,
                      const int* __restrict__ targets,
                      const unsigned long long* __restrict__ masks,
                      float* __restrict__ parts) {
    __shared__ unsigned long long rowsm[40][4];   // window masks (y halo 16)
    __shared__ unsigned long long big[8 * 18];    // [y][c][lvl0..3], 144B/row pad
    __shared__ float sred[4][9];

    int bid = blockIdx.x;
    int bx = bid % 12, by = (bid / 12) % 48, b = bid / TPI;
    int x0 = bx * 32, y0 = by * 8;
    int tid = threadIdx.x, lane = tid & 63, wv = tid >> 6;
    const int* tg = targets + b * HW;

    // ---- stage 40 rows x 4 classes of 64-bit windows: 1 thread each ----
    if (tid < 160) {
        int r = tid >> 2, cc = tid & 3;
        int yaS = y0 - 16 + r;
        unsigned long long wmask = 0ull;
        if (yaS >= 0 && yaS < H) {
            const unsigned long long* mrow =
                masks + ((size_t)(b * H + yaS)) * 24 + cc * 6;
            int bitpos = x0 - 16;                 // window start bit in image
            int iw = bitpos >> 6, sh = bitpos & 63;   // sh in {16,48}
            unsigned long long lo = (iw >= 0) ? mrow[iw] : 0ull;
            unsigned long long hi = (iw + 1 < 6) ? mrow[iw + 1] : 0ull;
            wmask = (lo >> sh) | (hi << (64 - sh));
        }
        rowsm[r][cc] = wmask;
    }
    __syncthreads();

    // ---- pre-OR +-dy pairs: one u64 for threads 0..127 ----
    if (tid < 128) {
        int yy = tid >> 4, c = (tid >> 2) & 3, lvl = tid & 3;
        unsigned long long v = (lvl == 0)
            ? rowsm[16 + yy][c]
            : (rowsm[16 + yy - lvl][c] | rowsm[16 + yy + lvl][c]);
        big[yy * 18 + c * 4 + lvl] = v;
    }
    __syncthreads();

    // ---- per-pixel fused loss: 1 pixel per thread ----
    int x = tid & 31, y = tid >> 5;               // y in [0,8)
    int xa = x0 + x, ya = y0 + y, ly = y + 16;
    int lx = x + 16, shl = 63 - lx;

    float red[9];
    #pragma unroll
    for (int j = 0; j < 9; ++j) red[j] = 0.0f;

    const float* ob = outputs + (size_t)b * CHW + (size_t)ya * W + xa;
    float e0 = exp2f(ob[0] * LOG2E);
    float e1 = exp2f(ob[HW] * LOG2E);
    float e2 = exp2f(ob[2 * HW] * LOG2E);
    float e3 = exp2f(ob[3 * HW] * LOG2E);
    float inv = 1.0f / (e0 + e1 + e2 + e3);
    float pr[4] = {e0 * inv, e1 * inv, e2 * inv, e3 * inv};

    #pragma unroll
    for (int c = 0; c < 4; ++c) {
        const ulonglong2* pp = (const ulonglong2*)&big[y * 18 + c * 4];
        ulonglong2 v0 = pp[0], v1 = pp[1];
        int n0 = nearest2(v0.x, lx, shl);       // dy = 0
        int n1 = nearest2(v0.y, lx, shl) + 1;   // |dy| = 1
        int n2 = nearest2(v1.x, lx, shl) + 4;   // |dy| = 2
        int n3 = nearest2(v1.y, lx, shl) + 9;   // |dy| = 3
        int best = min(min(n0, n1), min(n2, n3));
        if (best > 16) {                        // rare: exact extension
            for (int dy = 4; dy <= 16 && dy * dy < best; ++dy) {
                unsigned long long m = rowsm[ly + dy][c] | rowsm[ly - dy][c];
                if (m) best = min(best, dy * dy + nearest2(m, lx, shl));
            }
            if (best > 289) {
                best = min(best, BIG2);
                best = ring_fallback(tg, xa, ya, c, best);
            }
        }
        float dt = sqrtf((float)best);          // exact int < 2^24
        red[0] += pr[c] * dt;                   // target class: dt==0
        if ((v0.x >> lx) & 1ull) red[1 + c] += pr[c];   // T contribution
        red[5 + c] = fmaxf(red[5 + c], dt);     // slice max candidate
    }

    // ---- block reduce: red[0..4] sum, red[5..8] max ----
    #pragma unroll
    for (int off = 32; off > 0; off >>= 1) {
        #pragma unroll
        for (int j = 0; j < 5; ++j) red[j] += __shfl_down(red[j], off);
        #pragma unroll
        for (int j = 5; j < 9; ++j) red[j] = fmaxf(red[j], __shfl_down(red[j], off));
    }
    if (lane == 0) {
        #pragma unroll
        for (int j = 0; j < 9; ++j) sred[wv][j] = red[j];
    }
    __syncthreads();
    if (tid == 0) {
        float o[9];
        #pragma unroll
        for (int j = 0; j < 9; ++j) o[j] = sred[0][j];
        #pragma unroll
        for (int w = 1; w < 4; ++w) {
            #pragma unroll
            for (int j = 0; j < 5; ++j) o[j] += sred[w][j];
            #pragma unroll
            for (int j = 5; j < 9; ++j) o[j] = fmaxf(o[j], sred[w][j]);
        }
        // SoA: plane j contiguous over blocks -> coalesced finalize reads
        #pragma unroll
        for (int j = 0; j < 9; ++j) parts[j * NBLK + bid] = o[j];
    }
}

// Single block: reduce 4608 block partials (SoA planes) -> scalar loss.
__global__ __launch_bounds__(256)
void finalize(const float* __restrict__ parts, float* __restrict__ out) {
    __shared__ double asum[4];
    __shared__ double Tsh[32];
    __shared__ float Msh[32];
    int tid = threadIdx.x, lane = tid & 63, wv = tid >> 6;

    double a = 0.0;
    for (int i = tid; i < NBLK; i += 256) a += (double)parts[i];   // plane 0
    #pragma unroll
    for (int off = 32; off > 0; off >>= 1) a += __shfl_down(a, off);
    if (lane == 0) asum[wv] = a;

    for (int k = 0; k < 8; ++k) {
        int s = wv * 8 + k;
        int bb = s >> 2, cc = s & 3;
        double ts = 0.0;
        float ms = 0.0f;
        for (int i = lane; i < TPI; i += 64) {
            int blk = bb * TPI + i;
            ts += (double)parts[(1 + cc) * NBLK + blk];     // coalesced
            ms = fmaxf(ms, parts[(5 + cc) * NBLK + blk]);   // coalesced
        }
        #pragma unroll
        for (int off = 32; off > 0; off >>= 1) {
            ts += __shfl_down(ts, off);
            ms = fmaxf(ms, __shfl_down(ms, off));
        }
        if (lane == 0) { Tsh[s] = ts; Msh[s] = ms; }
    }
    __syncthreads();
    if (tid == 0) {
        double A = asum[0] + asum[1] + asum[2] + asum[3];
        double st = 0.0;
        for (int s = 0; s < 32; ++s) st += (double)Msh[s] * Tsh[s];
        out[0] = (float)((A - st) / ((double)C * (double)NTOT));
    }
}

extern "C" void kernel_launch(void* const* d_in, const int* in_sizes, int n_in,
                              void* d_out, int out_size, void* d_ws, size_t ws_size,
                              hipStream_t stream) {
    const float* outputs = (const float*)d_in[0];
    const int* targets = (const int*)d_in[1];
    float* out = (float*)d_out;
    // workspace layout:
    float* parts = (float*)d_ws;                                   // 165,888 B
    unsigned long long* masks =
        (unsigned long long*)((char*)d_ws + 256 * 1024);           // 589,824 B

    build_masks<<<NSEG / 4, 256, 0, stream>>>(targets, masks);
    dist_loss_kernel<<<NBLK, 256, 0, stream>>>(outputs, targets, masks, parts);
    finalize<<<1, 256, 0, stream>>>(parts, out);
}

// Round 4
// 115.692 us; speedup vs baseline: 1.0033x; 1.0033x over previous
//
#include <hip/hip_runtime.h>

#define B 8
#define C 4
#define H 384
#define W 384
#define HW (H * W)
#define CHW (C * H * W)
#define NTOT (B * CHW)        // 4,718,592
#define BIG2 589824           // 768^2, reference's BIG cap squared
#define TPI 288               // tiles per image (6 wd x 48 ytiles of 64x8)
#define NBLK (B * TPI)        // 2304
#define LOG2E 1.44269504088896340736f

// Exact Chebyshev-ring global-memory scan (essentially never taken: only
// when no class-c pixel exists in rows +-3 x cols +-63 of the query).
__device__ __attribute__((noinline))
int ring_fallback(const int* __restrict__ tg, int xa, int ya, int c, int best) {
    for (int d = 4; d * d < best; ++d) {
        int xlo = xa - d, xhi = xa + d, ylo = ya - d, yhi = ya + d;
        for (int xx = max(xlo, 0); xx <= min(xhi, W - 1); ++xx) {
            int ddx = xx - xa;
            int bb = ddx * ddx + d * d;
            if (bb < best) {
                if (ylo >= 0 && tg[ylo * W + xx] == c) best = bb;
                if (yhi < H && tg[yhi * W + xx] == c) best = min(best, bb);
            }
        }
        for (int yy = max(ylo + 1, 0); yy <= min(yhi - 1, H - 1); ++yy) {
            int ddy = yy - ya;
            int bb = ddy * ddy + d * d;
            if (bb < best) {
                if (xlo >= 0 && tg[yy * W + xlo] == c) best = bb;
                if (xhi < W && tg[yy * W + xhi] == c) best = min(best, bb);
            }
        }
    }
    return best;
}

// One 512-thread block per 64x8 tile; one WAVE per 64-px pixel row
// (lane = pixel). Staging: 42 ballot-tasks (14 rows x 3 words) build the
// class masks for rows y0-3..y0+10, words wd-1..wd+1 into 1.3 KB LDS.
// ONE barrier, then each wave scans independently: per class, 4 dy-levels,
// each a full 64-bit left/right window with +-63 x-reach via neighbor-word
// funnel shifts. No mask-precompute kernel, no pre-OR phase, no fences.
__global__ __launch_bounds__(512)
void dist_loss_kernel(const float* __restrict__ outputs,
                      const int* __restrict__ targets,
                      float* __restrict__ parts) {
    __shared__ unsigned long long rowsm[14][3][4];   // [row][word][class]
    __shared__ float sred[8][9];

    int bid = blockIdx.x;
    int b = bid / TPI;
    int r = bid % TPI;
    int wd = r / 48, yt = r % 48;         // word-column 0..5, ytile 0..47
    int tid = threadIdx.x, lane = tid & 63, wy = tid >> 6;   // wy in [0,8)
    const int* tg = targets + b * HW;
    int yr0 = yt * 8 - 3;

    int xa = wd * 64 + lane;
    int ya = yt * 8 + wy;

    // ---- issue outputs loads first: HBM latency hides under staging ----
    const float* ob = outputs + (size_t)b * CHW + (size_t)ya * W + xa;
    float o0 = ob[0], o1 = ob[HW], o2 = ob[2 * HW], o3 = ob[3 * HW];

    // ---- stage 14 rows x 3 words x 4 classes via ballot ----
    for (int t = wy; t < 42; t += 8) {
        int rr = t / 3, wi = t % 3;
        int yr = yr0 + rr, wg = wd - 1 + wi;
        int tv = -1;
        if (yr >= 0 && yr < H && wg >= 0 && wg < 6)
            tv = tg[yr * W + wg * 64 + lane];
        unsigned long long m0 = __ballot(tv == 0);
        unsigned long long m1 = __ballot(tv == 1);
        unsigned long long m2 = __ballot(tv == 2);
        unsigned long long m3 = __ballot(tv == 3);
        if (lane == 0) {
            rowsm[rr][wi][0] = m0; rowsm[rr][wi][1] = m1;
            rowsm[rr][wi][2] = m2; rowsm[rr][wi][3] = m3;
        }
    }
    __syncthreads();

    // ---- softmax (from pre-issued loads) ----
    float e0 = exp2f(o0 * LOG2E);
    float e1 = exp2f(o1 * LOG2E);
    float e2 = exp2f(o2 * LOG2E);
    float e3 = exp2f(o3 * LOG2E);
    float inv = 1.0f / (e0 + e1 + e2 + e3);
    float pr[4] = {e0 * inv, e1 * inv, e2 * inv, e3 * inv};

    int rs = wy + 3;                       // own row index in rowsm
    float red[9];
    #pragma unroll
    for (int j = 0; j < 9; ++j) red[j] = 0.0f;

    #pragma unroll
    for (int c = 0; c < 4; ++c) {
        // per-wave dy-level pre-OR (9 u64 ORs, register-resident)
        unsigned long long lvl[4][3];
        #pragma unroll
        for (int wi = 0; wi < 3; ++wi) {
            lvl[0][wi] = rowsm[rs][wi][c];
            lvl[1][wi] = rowsm[rs - 1][wi][c] | rowsm[rs + 1][wi][c];
            lvl[2][wi] = rowsm[rs - 2][wi][c] | rowsm[rs + 2][wi][c];
            lvl[3][wi] = rowsm[rs - 3][wi][c] | rowsm[rs + 3][wi][c];
        }
        int best = 0x7fffffff;
        #pragma unroll
        for (int k = 0; k < 4; ++k) {
            unsigned long long wm = lvl[k][0], w0 = lvl[k][1], wp = lvl[k][2];
            // right: bit j = pixel at dx=+j (j=0..63); left: bit 63-j = dx=-j
            unsigned long long rgt = (w0 >> lane) | ((wp << 1) << (63 - lane));
            unsigned long long lft = (w0 << (63 - lane)) | ((wm >> lane) >> 1);
            int dR = rgt ? (int)__builtin_ctzll(rgt) : 999;
            int dL = lft ? (int)__builtin_clzll(lft) : 999;
            int d = min(dR, dL);
            best = min(best, d * d + k * k);
        }
        if (best > 16) {                    // empty 7x127 window: adversarial only
            best = min(best, BIG2);
            best = ring_fallback(tg, xa, ya, c, best);
        }
        float dt = sqrtf((float)best);      // exact int < 2^24
        red[0] += pr[c] * dt;               // target class: dt==0
        if ((lvl[0][1] >> lane) & 1ull) red[1 + c] += pr[c];   // T contribution
        red[5 + c] = fmaxf(red[5 + c], dt); // slice max candidate
    }

    // ---- wave reduce: red[0..4] sum, red[5..8] max ----
    #pragma unroll
    for (int off = 32; off > 0; off >>= 1) {
        #pragma unroll
        for (int j = 0; j < 5; ++j) red[j] += __shfl_down(red[j], off);
        #pragma unroll
        for (int j = 5; j < 9; ++j) red[j] = fmaxf(red[j], __shfl_down(red[j], off));
    }
    if (lane == 0) {
        #pragma unroll
        for (int j = 0; j < 9; ++j) sred[wy][j] = red[j];
    }
    __syncthreads();

    // ---- cross-wave reduce by wave 0 (lanes 0..7 hold one wave each) ----
    if (wy == 0) {
        float v[9];
        #pragma unroll
        for (int j = 0; j < 9; ++j) v[j] = (lane < 8) ? sred[lane][j] : 0.0f;
        #pragma unroll
        for (int off = 4; off > 0; off >>= 1) {
            #pragma unroll
            for (int j = 0; j < 5; ++j) v[j] += __shfl_down(v[j], off);
            #pragma unroll
            for (int j = 5; j < 9; ++j) v[j] = fmaxf(v[j], __shfl_down(v[j], off));
        }
        if (lane == 0) {
            // SoA: plane j contiguous over blocks -> coalesced finalize reads
            #pragma unroll
            for (int j = 0; j < 9; ++j) parts[j * NBLK + bid] = v[j];
        }
    }
}

// Single block: reduce 2304 block partials (SoA planes) -> scalar loss.
__global__ __launch_bounds__(256)
void finalize(const float* __restrict__ parts, float* __restrict__ out) {
    __shared__ double asum[4];
    __shared__ double Tsh[32];
    __shared__ float Msh[32];
    int tid = threadIdx.x, lane = tid & 63, wv = tid >> 6;

    double a = 0.0;
    for (int i = tid; i < NBLK; i += 256) a += (double)parts[i];   // plane 0
    #pragma unroll
    for (int off = 32; off > 0; off >>= 1) a += __shfl_down(a, off);
    if (lane == 0) asum[wv] = a;

    for (int k = 0; k < 8; ++k) {
        int s = wv * 8 + k;
        int bb = s >> 2, cc = s & 3;
        double ts = 0.0;
        float ms = 0.0f;
        for (int i = lane; i < TPI; i += 64) {
            int blk = bb * TPI + i;
            ts += (double)parts[(1 + cc) * NBLK + blk];     // coalesced
            ms = fmaxf(ms, parts[(5 + cc) * NBLK + blk]);   // coalesced
        }
        #pragma unroll
        for (int off = 32; off > 0; off >>= 1) {
            ts += __shfl_down(ts, off);
            ms = fmaxf(ms, __shfl_down(ms, off));
        }
        if (lane == 0) { Tsh[s] = ts; Msh[s] = ms; }
    }
    __syncthreads();
    if (tid == 0) {
        double A = asum[0] + asum[1] + asum[2] + asum[3];
        double st = 0.0;
        for (int s = 0; s < 32; ++s) st += (double)Msh[s] * Tsh[s];
        out[0] = (float)((A - st) / ((double)C * (double)NTOT));
    }
}

extern "C" void kernel_launch(void* const* d_in, const int* in_sizes, int n_in,
                              void* d_out, int out_size, void* d_ws, size_t ws_size,
                              hipStream_t stream) {
    const float* outputs = (const float*)d_in[0];
    const int* targets = (const int*)d_in[1];
    float* out = (float*)d_out;
    float* parts = (float*)d_ws;   // 9 planes x NBLK floats = 82,944 B (SoA)

    dist_loss_kernel<<<NBLK, 512, 0, stream>>>(outputs, targets, parts);
    finalize<<<1, 256, 0, stream>>>(parts, out);
}

// Round 5
// 94.392 us; speedup vs baseline: 1.2297x; 1.2257x over previous
//
#include <hip/hip_runtime.h>

#define B 8
#define C 4
#define H 384
#define W 384
#define HW (H * W)
#define CHW (C * H * W)
#define NTOT (B * CHW)        // 4,718,592
#define BIG2 589824           // 768^2, reference's BIG cap squared
#define TPI 144               // tiles per image (12x12 of 32x32)
#define NBLK (B * TPI)        // 1152
#define NSEG (B * H * 6)      // 18432 row-segments of 64 px
#define LOG2E 1.44269504088896340736f

// Full-width 64-bit scan (slow/rare paths only). min over set bits p of
// (p - lx)^2 ; 999 sentinel if empty side. lx in [16,48).
__device__ __forceinline__ int nearest2(unsigned long long m, int lx, int shl) {
    unsigned long long right = m >> lx;
    int dR = right ? (int)__builtin_ctzll(right) : 999;
    unsigned long long leftb = m << shl;            // shl = 63 - lx
    int dL = leftb ? (int)__builtin_clzll(leftb) : 999;
    int d = min(dR, dL);
    return d * d;
}

// Windowed 32-bit scan. right: bit0 = own pixel, bit k = dx=+k (reach 31).
// left: bit31 = own pixel, bit 30 = dx=-1, ... (reach >= 16). Sentinel 999
// keeps the ">289 -> ring" exactness invariant identical to nearest2's.
__device__ __forceinline__ int scan32(unsigned int right, unsigned int left, int add) {
    int dR = right ? __builtin_ctz(right) : 999;
    int dL = left ? __builtin_clz(left) : 999;
    int d = min(dR, dL);
    return d * d + add;
}

// Exact Chebyshev-ring global-memory scan (essentially never taken).
__device__ __attribute__((noinline))
int ring_fallback(const int* __restrict__ tg, int xa, int ya, int c, int best) {
    for (int d = 17; d * d < best; ++d) {
        int xlo = xa - d, xhi = xa + d, ylo = ya - d, yhi = ya + d;
        for (int xx = max(xlo, 0); xx <= min(xhi, W - 1); ++xx) {
            int ddx = xx - xa;
            int bb = ddx * ddx + d * d;
            if (bb < best) {
                if (ylo >= 0 && tg[ylo * W + xx] == c) best = bb;
                if (yhi < H && tg[yhi * W + xx] == c) best = min(best, bb);
            }
        }
        for (int yy = max(ylo + 1, 0); yy <= min(yhi - 1, H - 1); ++yy) {
            int ddy = yy - ya;
            int bb = ddy * ddy + d * d;
            if (bb < best) {
                if (xlo >= 0 && tg[yy * W + xlo] == c) best = bb;
                if (xhi < W && tg[yy * W + xhi] == c) best = min(best, bb);
            }
        }
    }
    return best;
}

// Build per-class row bitmasks once: masks[(b*H+y)*24 + c*6 + word].
// One wave per 64-px row segment; 4 ballots; lane0 writes 4 u64.
__global__ __launch_bounds__(256)
void build_masks(const int* __restrict__ targets,
                 unsigned long long* __restrict__ masks) {
    int wv = threadIdx.x >> 6, lane = threadIdx.x & 63;
    int seg = blockIdx.x * 4 + wv;
    if (seg >= NSEG) return;
    int wd = seg % 6, rem = seg / 6;          // rem = b*H + y
    int tv = targets[rem * W + wd * 64 + lane];
    unsigned long long m0 = __ballot(tv == 0);
    unsigned long long m1 = __ballot(tv == 1);
    unsigned long long m2 = __ballot(tv == 2);
    unsigned long long m3 = __ballot(tv == 3);
    if (lane == 0) {
        unsigned long long* dst = masks + (size_t)rem * 24 + wd;
        dst[0]  = m0;
        dst[6]  = m1;
        dst[12] = m2;
        dst[18] = m3;
    }
}

// R1's proven structure (32x32 tile, 1152 blocks, 4 px/thread, windowed
// 32-bit scans) with ONLY the staging phase replaced: instead of 16 serial
// {strided load + 4 ballots} iterations, each thread funnel-shifts one
// (row, class) 64-bit window from the precomputed global masks (2 L2-hit
// u64 loads). Outputs float4 loads issued before staging to hide latency.
__global__ __launch_bounds__(256)
void dist_loss_kernel(const float* __restrict__ outputs,
                      const int* __restrict__ targets,
                      const unsigned long long* __restrict__ masks,
                      float* __restrict__ parts) {
    __shared__ unsigned long long rowsm[64][4];   // window masks (y halo 16)
    __shared__ unsigned long long big[32 * 18];   // [y][c][lvl0..3], 144B/row pad
    __shared__ float sred[4][9];

    int bid = blockIdx.x;
    int bx = bid % 12, by = (bid / 12) % 12, b = bid / TPI;
    int x0 = bx * 32, y0 = by * 32;
    int tid = threadIdx.x, lane = tid & 63, wv = tid >> 6;
    const int* tg = targets + b * HW;

    // pixel-quad coords (used by softmax + hot loop)
    int xq = (tid & 7) * 4;                 // 0,4,...,28
    int y = tid >> 3;                       // 0..31
    int ya = y0 + y, ly = y + 16;

    // ---- issue outputs loads first: HBM latency hides under staging ----
    const float* ob = outputs + (size_t)b * CHW + (size_t)ya * W + (x0 + xq);
    float4 f0 = *(const float4*)ob;
    float4 f1 = *(const float4*)(ob + HW);
    float4 f2 = *(const float4*)(ob + 2 * HW);
    float4 f3 = *(const float4*)(ob + 3 * HW);

    // ---- stage 64 rows x 4 classes of 64-bit windows: 1 thread each ----
    {
        int r = tid >> 2, cc = tid & 3;
        int yaS = y0 - 16 + r;
        unsigned long long wmask = 0ull;
        if (yaS >= 0 && yaS < H) {
            const unsigned long long* mrow =
                masks + ((size_t)(b * H + yaS)) * 24 + cc * 6;
            int bitpos = x0 - 16;                 // window start bit in image
            int iw = bitpos >> 6, sh = bitpos & 63;   // sh in {16,48}
            unsigned long long lo = (iw >= 0) ? mrow[iw] : 0ull;
            unsigned long long hi = (iw + 1 < 6) ? mrow[iw + 1] : 0ull;
            wmask = (lo >> sh) | (hi << (64 - sh));
        }
        rowsm[tid >> 2][cc] = wmask;
    }
    __syncthreads();

    // ---- pre-OR +-dy pairs: two u64 per thread ----
    #pragma unroll
    for (int q = 0; q < 2; ++q) {
        int idx = tid + 256 * q;            // 0..511
        int yy = idx >> 4, c = (idx >> 2) & 3, lvl = idx & 3;
        unsigned long long v = (lvl == 0)
            ? rowsm[16 + yy][c]
            : (rowsm[16 + yy - lvl][c] | rowsm[16 + yy + lvl][c]);
        big[yy * 18 + c * 4 + lvl] = v;
    }
    __syncthreads();

    float red[9];
    #pragma unroll
    for (int j = 0; j < 9; ++j) red[j] = 0.0f;

    // softmax probabilities for the 4 pixels (from pre-issued float4 loads)
    float pr[4][4];                         // [class][pixel]
    {
        const float* fc0 = (const float*)&f0;
        const float* fc1 = (const float*)&f1;
        const float* fc2 = (const float*)&f2;
        const float* fc3 = (const float*)&f3;
        #pragma unroll
        for (int p = 0; p < 4; ++p) {
            float e0 = exp2f(fc0[p] * LOG2E);
            float e1 = exp2f(fc1[p] * LOG2E);
            float e2 = exp2f(fc2[p] * LOG2E);
            float e3 = exp2f(fc3[p] * LOG2E);
            float inv = 1.0f / (e0 + e1 + e2 + e3);
            pr[0][p] = e0 * inv; pr[1][p] = e1 * inv;
            pr[2][p] = e2 * inv; pr[3][p] = e3 * inv;
        }
    }

    #pragma unroll
    for (int c = 0; c < 4; ++c) {
        const ulonglong2* pp = (const ulonglong2*)&big[y * 18 + c * 4];
        ulonglong2 va = pp[0], vb = pp[1];
        unsigned long long r0 = va.x >> xq;     // dy = 0   (bit 16+p = pixel p)
        unsigned long long r1 = va.y >> xq;     // |dy| = 1
        unsigned long long r2 = vb.x >> xq;     // |dy| = 2
        unsigned long long r3 = vb.y >> xq;     // |dy| = 3
        unsigned int l0 = (unsigned int)r0, l1 = (unsigned int)r1;
        unsigned int l2 = (unsigned int)r2, l3 = (unsigned int)r3;
        #pragma unroll
        for (int p = 0; p < 4; ++p) {
            unsigned int w0r = (unsigned int)(r0 >> (16 + p));
            unsigned int w1r = (unsigned int)(r1 >> (16 + p));
            unsigned int w2r = (unsigned int)(r2 >> (16 + p));
            unsigned int w3r = (unsigned int)(r3 >> (16 + p));
            unsigned int w0l = l0 << (15 - p);
            unsigned int w1l = l1 << (15 - p);
            unsigned int w2l = l2 << (15 - p);
            unsigned int w3l = l3 << (15 - p);
            int best = scan32(w0r, w0l, 0);
            best = min(best, scan32(w1r, w1l, 1));
            best = min(best, scan32(w2r, w2l, 4));
            best = min(best, scan32(w3r, w3l, 9));
            if (best > 16) {                    // rare: exact extension
                int lx = 16 + xq + p, shl = 63 - lx;
                for (int dy = 4; dy <= 16 && dy * dy < best; ++dy) {
                    unsigned long long mm = rowsm[ly + dy][c] | rowsm[ly - dy][c];
                    if (mm) best = min(best, dy * dy + nearest2(mm, lx, shl));
                }
                if (best > 289) {
                    best = min(best, BIG2);
                    best = ring_fallback(tg, x0 + xq + p, ya, c, best);
                }
            }
            float dt = sqrtf((float)best);      // exact int < 2^24
            red[0] += pr[c][p] * dt;            // target class: dt==0
            if (w0r & 1u) red[1 + c] += pr[c][p];   // T contribution
            red[5 + c] = fmaxf(red[5 + c], dt); // slice max candidate
        }
    }

    // ---- block reduce: red[0..4] sum, red[5..8] max ----
    #pragma unroll
    for (int off = 32; off > 0; off >>= 1) {
        #pragma unroll
        for (int j = 0; j < 5; ++j) red[j] += __shfl_down(red[j], off);
        #pragma unroll
        for (int j = 5; j < 9; ++j) red[j] = fmaxf(red[j], __shfl_down(red[j], off));
    }
    if (lane == 0) {
        #pragma unroll
        for (int j = 0; j < 9; ++j) sred[wv][j] = red[j];
    }
    __syncthreads();
    if (tid == 0) {
        float o[9];
        #pragma unroll
        for (int j = 0; j < 9; ++j) o[j] = sred[0][j];
        #pragma unroll
        for (int w = 1; w < 4; ++w) {
            #pragma unroll
            for (int j = 0; j < 5; ++j) o[j] += sred[w][j];
            #pragma unroll
            for (int j = 5; j < 9; ++j) o[j] = fmaxf(o[j], sred[w][j]);
        }
        // SoA: plane j contiguous over blocks -> coalesced finalize reads
        #pragma unroll
        for (int j = 0; j < 9; ++j) parts[j * NBLK + bid] = o[j];
    }
}

// Single block: reduce 1152 block partials (SoA planes) -> scalar loss.
__global__ __launch_bounds__(256)
void finalize(const float* __restrict__ parts, float* __restrict__ out) {
    __shared__ double asum[4];
    __shared__ double Tsh[32];
    __shared__ float Msh[32];
    int tid = threadIdx.x, lane = tid & 63, wv = tid >> 6;

    double a = 0.0;
    for (int i = tid; i < NBLK; i += 256) a += (double)parts[i];   // plane 0
    #pragma unroll
    for (int off = 32; off > 0; off >>= 1) a += __shfl_down(a, off);
    if (lane == 0) asum[wv] = a;

    for (int k = 0; k < 8; ++k) {
        int s = wv * 8 + k;
        int bb = s >> 2, cc = s & 3;
        double ts = 0.0;
        float ms = 0.0f;
        for (int i = lane; i < TPI; i += 64) {
            int blk = bb * TPI + i;
            ts += (double)parts[(1 + cc) * NBLK + blk];     // coalesced
            ms = fmaxf(ms, parts[(5 + cc) * NBLK + blk]);   // coalesced
        }
        #pragma unroll
        for (int off = 32; off > 0; off >>= 1) {
            ts += __shfl_down(ts, off);
            ms = fmaxf(ms, __shfl_down(ms, off));
        }
        if (lane == 0) { Tsh[s] = ts; Msh[s] = ms; }
    }
    __syncthreads();
    if (tid == 0) {
        double A = asum[0] + asum[1] + asum[2] + asum[3];
        double st = 0.0;
        for (int s = 0; s < 32; ++s) st += (double)Msh[s] * Tsh[s];
        out[0] = (float)((A - st) / ((double)C * (double)NTOT));
    }
}

extern "C" void kernel_launch(void* const* d_in, const int* in_sizes, int n_in,
                              void* d_out, int out_size, void* d_ws, size_t ws_size,
                              hipStream_t stream) {
    const float* outputs = (const float*)d_in[0];
    const int* targets = (const int*)d_in[1];
    float* out = (float*)d_out;
    // workspace layout:
    float* parts = (float*)d_ws;                                   // 41,472 B
    unsigned long long* masks =
        (unsigned long long*)((char*)d_ws + 64 * 1024);            // 589,824 B

    build_masks<<<NSEG / 4, 256, 0, stream>>>(targets, masks);
    dist_loss_kernel<<<NBLK, 256, 0, stream>>>(outputs, targets, masks, parts);
    finalize<<<1, 256, 0, stream>>>(parts, out);
}

// Round 6
// 93.183 us; speedup vs baseline: 1.2456x; 1.0130x over previous
//
#include <hip/hip_runtime.h>

#define B 8
#define C 4
#define H 384
#define W 384
#define HW (H * W)
#define CHW (C * H * W)
#define NTOT (B * CHW)        // 4,718,592
#define BIG2 589824           // 768^2, reference's BIG cap squared
#define TPI 144               // tiles per image (12x12 of 32x32)
#define NBLK (B * TPI)        // 1152
#define NSEG (B * H * 6)      // 18432 row-segments of 64 px
#define LOG2E 1.44269504088896340736f

// Full-width 64-bit scan (slow/rare paths only). min over set bits p of
// (p - lx)^2 ; 999 sentinel if empty side. lx in [16,48).
__device__ __forceinline__ int nearest2(unsigned long long m, int lx, int shl) {
    unsigned long long right = m >> lx;
    int dR = right ? (int)__builtin_ctzll(right) : 999;
    unsigned long long leftb = m << shl;            // shl = 63 - lx
    int dL = leftb ? (int)__builtin_clzll(leftb) : 999;
    int d = min(dR, dL);
    return d * d;
}

// Windowed 32-bit scan, sentinel-bit form (no cmp/cndmask guards).
// right: bit0 = own pixel, bit k = dx=+k; left: bit31 = own, bit31-k = dx=-k.
// Sentinel bit forces nonzero input -> plain v_ffbl/v_ffbh; empty side reads
// as d=31 -> >= 961, which the rare path promotes to BIG2 before the exact
// ring fallback (conflated far pixels are rediscovered there exactly).
__device__ __forceinline__ int scan32f(unsigned int right, unsigned int left, int add) {
    int dR = __builtin_ctz(right | 0x80000000u);
    int dL = __builtin_clz(left | 1u);
    int d = min(dR, dL);
    return d * d + add;
}

// Exact Chebyshev-ring global-memory scan (essentially never taken).
__device__ __attribute__((noinline))
int ring_fallback(const int* __restrict__ tg, int xa, int ya, int c, int best) {
    for (int d = 17; d * d < best; ++d) {
        int xlo = xa - d, xhi = xa + d, ylo = ya - d, yhi = ya + d;
        for (int xx = max(xlo, 0); xx <= min(xhi, W - 1); ++xx) {
            int ddx = xx - xa;
            int bb = ddx * ddx + d * d;
            if (bb < best) {
                if (ylo >= 0 && tg[ylo * W + xx] == c) best = bb;
                if (yhi < H && tg[yhi * W + xx] == c) best = min(best, bb);
            }
        }
        for (int yy = max(ylo + 1, 0); yy <= min(yhi - 1, H - 1); ++yy) {
            int ddy = yy - ya;
            int bb = ddy * ddy + d * d;
            if (bb < best) {
                if (xlo >= 0 && tg[yy * W + xlo] == c) best = bb;
                if (xhi < W && tg[yy * W + xhi] == c) best = min(best, bb);
            }
        }
    }
    return best;
}

// Build per-class row bitmasks once: masks[(b*H+y)*24 + c*6 + word].
// One wave per 64-px row segment; 4 ballots; lane0 writes 4 u64.
__global__ __launch_bounds__(256)
void build_masks(const int* __restrict__ targets,
                 unsigned long long* __restrict__ masks) {
    int wv = threadIdx.x >> 6, lane = threadIdx.x & 63;
    int seg = blockIdx.x * 4 + wv;
    if (seg >= NSEG) return;
    int wd = seg % 6, rem = seg / 6;          // rem = b*H + y
    int tv = targets[rem * W + wd * 64 + lane];
    unsigned long long m0 = __ballot(tv == 0);
    unsigned long long m1 = __ballot(tv == 1);
    unsigned long long m2 = __ballot(tv == 2);
    unsigned long long m3 = __ballot(tv == 3);
    if (lane == 0) {
        unsigned long long* dst = masks + (size_t)rem * 24 + wd;
        dst[0]  = m0;
        dst[6]  = m1;
        dst[12] = m2;
        dst[18] = m3;
    }
}

// 32x32 tile per block, 512 threads, 2 px/thread (9216 waves = 9/SIMD:
// latency-hiding fix vs the 4.5 waves/SIMD 256-thread version). Staging:
// threads 0..255 funnel-shift one (row, class) 64-bit window from the
// precomputed global masks. Pre-OR is exactly 1 task/thread. Hot loop uses
// sentinel-bit scans (no cndmask guards).
__global__ __launch_bounds__(512)
void dist_loss_kernel(const float* __restrict__ outputs,
                      const int* __restrict__ targets,
                      const unsigned long long* __restrict__ masks,
                      float* __restrict__ parts) {
    __shared__ unsigned long long rowsm[64][4];   // window masks (y halo 16)
    __shared__ unsigned long long big[32 * 18];   // [y][c][lvl0..3], 144B/row pad
    __shared__ float sred[8][9];

    int bid = blockIdx.x;
    int bx = bid % 12, by = (bid / 12) % 12, b = bid / TPI;
    int x0 = bx * 32, y0 = by * 32;
    int tid = threadIdx.x, lane = tid & 63, wv = tid >> 6;
    const int* tg = targets + b * HW;

    // pixel-pair coords
    int x2 = (tid & 15) * 2;                // 0,2,...,30
    int y = tid >> 4;                       // 0..31
    int ya = y0 + y, ly = y + 16;

    // ---- issue outputs loads first: HBM latency hides under staging ----
    const float* ob = outputs + (size_t)b * CHW + (size_t)ya * W + (x0 + x2);
    float2 f0 = *(const float2*)ob;
    float2 f1 = *(const float2*)(ob + HW);
    float2 f2 = *(const float2*)(ob + 2 * HW);
    float2 f3 = *(const float2*)(ob + 3 * HW);

    // ---- stage 64 rows x 4 classes of 64-bit windows: threads 0..255 ----
    if (tid < 256) {
        int r = tid >> 2, cc = tid & 3;
        int yaS = y0 - 16 + r;
        unsigned long long wmask = 0ull;
        if (yaS >= 0 && yaS < H) {
            const unsigned long long* mrow =
                masks + ((size_t)(b * H + yaS)) * 24 + cc * 6;
            int bitpos = x0 - 16;                 // window start bit in image
            int iw = bitpos >> 6, sh = bitpos & 63;   // sh in {16,48}
            unsigned long long lo = (iw >= 0) ? mrow[iw] : 0ull;
            unsigned long long hi = (iw + 1 < 6) ? mrow[iw + 1] : 0ull;
            wmask = (lo >> sh) | (hi << (64 - sh));
        }
        rowsm[r][cc] = wmask;
    }
    __syncthreads();

    // ---- pre-OR +-dy pairs: exactly one u64 per thread ----
    {
        int yy = tid >> 4, c = (tid >> 2) & 3, lvl = tid & 3;
        unsigned long long v = (lvl == 0)
            ? rowsm[16 + yy][c]
            : (rowsm[16 + yy - lvl][c] | rowsm[16 + yy + lvl][c]);
        big[yy * 18 + c * 4 + lvl] = v;
    }
    __syncthreads();

    float red[9];
    #pragma unroll
    for (int j = 0; j < 9; ++j) red[j] = 0.0f;

    // softmax probabilities for the 2 pixels
    float pr[4][2];                         // [class][pixel]
    {
        const float* fc0 = (const float*)&f0;
        const float* fc1 = (const float*)&f1;
        const float* fc2 = (const float*)&f2;
        const float* fc3 = (const float*)&f3;
        #pragma unroll
        for (int p = 0; p < 2; ++p) {
            float e0 = exp2f(fc0[p] * LOG2E);
            float e1 = exp2f(fc1[p] * LOG2E);
            float e2 = exp2f(fc2[p] * LOG2E);
            float e3 = exp2f(fc3[p] * LOG2E);
            float inv = 1.0f / (e0 + e1 + e2 + e3);
            pr[0][p] = e0 * inv; pr[1][p] = e1 * inv;
            pr[2][p] = e2 * inv; pr[3][p] = e3 * inv;
        }
    }

    #pragma unroll
    for (int c = 0; c < 4; ++c) {
        const ulonglong2* pp = (const ulonglong2*)&big[y * 18 + c * 4];
        ulonglong2 va = pp[0], vb = pp[1];
        unsigned long long r0 = va.x >> x2;     // dy = 0   (bit 16+p = pixel p)
        unsigned long long r1 = va.y >> x2;     // |dy| = 1
        unsigned long long r2 = vb.x >> x2;     // |dy| = 2
        unsigned long long r3 = vb.y >> x2;     // |dy| = 3
        unsigned int l0 = (unsigned int)r0, l1 = (unsigned int)r1;
        unsigned int l2 = (unsigned int)r2, l3 = (unsigned int)r3;
        #pragma unroll
        for (int p = 0; p < 2; ++p) {
            unsigned int w0r = (unsigned int)(r0 >> (16 + p));
            unsigned int w1r = (unsigned int)(r1 >> (16 + p));
            unsigned int w2r = (unsigned int)(r2 >> (16 + p));
            unsigned int w3r = (unsigned int)(r3 >> (16 + p));
            unsigned int w0l = l0 << (15 - p);
            unsigned int w1l = l1 << (15 - p);
            unsigned int w2l = l2 << (15 - p);
            unsigned int w3l = l3 << (15 - p);
            int best = scan32f(w0r, w0l, 0);
            best = min(best, scan32f(w1r, w1l, 1));
            best = min(best, scan32f(w2r, w2l, 4));
            best = min(best, scan32f(w3r, w3l, 9));
            if (best > 16) {                    // rare: exact extension
                int lx = 16 + x2 + p, shl = 63 - lx;
                for (int dy = 4; dy <= 16 && dy * dy < best; ++dy) {
                    unsigned long long mm = rowsm[ly + dy][c] | rowsm[ly - dy][c];
                    if (mm) best = min(best, dy * dy + nearest2(mm, lx, shl));
                }
                if (best > 289) {
                    // promote sentinel/conflated values (>= 961) to the BIG
                    // cap; ring is then exact (rediscovers any far pixel,
                    // returns BIG2 = 768^2 for absent classes = ref BIG).
                    if (best >= 961) best = BIG2;
                    best = ring_fallback(tg, x0 + x2 + p, ya, c, best);
                }
            }
            float dt = sqrtf((float)best);      // exact int < 2^24
            red[0] += pr[c][p] * dt;            // target class: dt==0
            if (w0r & 1u) red[1 + c] += pr[c][p];   // T contribution
            red[5 + c] = fmaxf(red[5 + c], dt); // slice max candidate
        }
    }

    // ---- block reduce: red[0..4] sum, red[5..8] max ----
    #pragma unroll
    for (int off = 32; off > 0; off >>= 1) {
        #pragma unroll
        for (int j = 0; j < 5; ++j) red[j] += __shfl_down(red[j], off);
        #pragma unroll
        for (int j = 5; j < 9; ++j) red[j] = fmaxf(red[j], __shfl_down(red[j], off));
    }
    if (lane == 0) {
        #pragma unroll
        for (int j = 0; j < 9; ++j) sred[wv][j] = red[j];
    }
    __syncthreads();

    // ---- cross-wave reduce by wave 0 (lanes 0..7 hold one wave each) ----
    if (wv == 0) {
        float v[9];
        #pragma unroll
        for (int j = 0; j < 9; ++j) v[j] = (lane < 8) ? sred[lane][j] : 0.0f;
        #pragma unroll
        for (int off = 4; off > 0; off >>= 1) {
            #pragma unroll
            for (int j = 0; j < 5; ++j) v[j] += __shfl_down(v[j], off);
            #pragma unroll
            for (int j = 5; j < 9; ++j) v[j] = fmaxf(v[j], __shfl_down(v[j], off));
        }
        if (lane == 0) {
            // SoA: plane j contiguous over blocks -> coalesced finalize reads
            #pragma unroll
            for (int j = 0; j < 9; ++j) parts[j * NBLK + bid] = v[j];
        }
    }
}

// Single block: reduce 1152 block partials (SoA planes) -> scalar loss.
__global__ __launch_bounds__(256)
void finalize(const float* __restrict__ parts, float* __restrict__ out) {
    __shared__ double asum[4];
    __shared__ double Tsh[32];
    __shared__ float Msh[32];
    int tid = threadIdx.x, lane = tid & 63, wv = tid >> 6;

    double a = 0.0;
    for (int i = tid; i < NBLK; i += 256) a += (double)parts[i];   // plane 0
    #pragma unroll
    for (int off = 32; off > 0; off >>= 1) a += __shfl_down(a, off);
    if (lane == 0) asum[wv] = a;

    for (int k = 0; k < 8; ++k) {
        int s = wv * 8 + k;
        int bb = s >> 2, cc = s & 3;
        double ts = 0.0;
        float ms = 0.0f;
        for (int i = lane; i < TPI; i += 64) {
            int blk = bb * TPI + i;
            ts += (double)parts[(1 + cc) * NBLK + blk];     // coalesced
            ms = fmaxf(ms, parts[(5 + cc) * NBLK + blk]);   // coalesced
        }
        #pragma unroll
        for (int off = 32; off > 0; off >>= 1) {
            ts += __shfl_down(ts, off);
            ms = fmaxf(ms, __shfl_down(ms, off));
        }
        if (lane == 0) { Tsh[s] = ts; Msh[s] = ms; }
    }
    __syncthreads();
    if (tid == 0) {
        double A = asum[0] + asum[1] + asum[2] + asum[3];
        double st = 0.0;
        for (int s = 0; s < 32; ++s) st += (double)Msh[s] * Tsh[s];
        out[0] = (float)((A - st) / ((double)C * (double)NTOT));
    }
}

extern "C" void kernel_launch(void* const* d_in, const int* in_sizes, int n_in,
                              void* d_out, int out_size, void* d_ws, size_t ws_size,
                              hipStream_t stream) {
    const float* outputs = (const float*)d_in[0];
    const int* targets = (const int*)d_in[1];
    float* out = (float*)d_out;
    // workspace layout:
    float* parts = (float*)d_ws;                                   // 41,472 B
    unsigned long long* masks =
        (unsigned long long*)((char*)d_ws + 64 * 1024);            // 589,824 B

    build_masks<<<NSEG / 4, 256, 0, stream>>>(targets, masks);
    dist_loss_kernel<<<NBLK, 512, 0, stream>>>(outputs, targets, masks, parts);
    finalize<<<1, 256, 0, stream>>>(parts, out);
}